// Round 7
// baseline (399.169 us; speedup 1.0000x reference)
//
#include <hip/hip_runtime.h>
#include <hip/hip_bf16.h>

using bf16 = __hip_bfloat16;
typedef short s16x8 __attribute__((ext_vector_type(8)));
typedef float f32x4 __attribute__((ext_vector_type(4)));
typedef unsigned short u16;

// ---------- helpers ----------
__device__ __forceinline__ void gld_lds16(const void* g, void* l) {
  __builtin_amdgcn_global_load_lds(
      (const __attribute__((address_space(1))) void*)g,
      (__attribute__((address_space(3))) void*)l, 16, 0, 0);
}

// ---------- fp32 -> bf16 elementwise convert ----------
__global__ __launch_bounds__(256) void convert_f32_bf16(
    const float* __restrict__ in, bf16* __restrict__ out, int n) {
  int i = blockIdx.x * 256 + threadIdx.x;
  if (i < n) out[i] = __float2bfloat16(in[i]);
}

// ---------- zero fp32 ----------
__global__ __launch_bounds__(256) void zero_f32(float* __restrict__ p, int n) {
  int i = blockIdx.x * 256 + threadIdx.x;
  if (i < n) p[i] = 0.f;
}

// ---------- transpose [C][inner] fp32 -> [inner][out_ld] bf16 ----------
__global__ __launch_bounds__(256) void transpose_f32_to_bf16(
    const float* __restrict__ in, bf16* __restrict__ out, int inner,
    long in_b, long out_b, int out_ld) {
  __shared__ float tile[32][33];
  const int bx = blockIdx.x;
  const int by = blockIdx.y;
  const int bz = blockIdx.z;
  const int tx = threadIdx.x & 31;
  const int ty = threadIdx.x >> 5;
  const float* ib = in + (long)bz * in_b;
  bf16* ob = out + (long)bz * out_b;
#pragma unroll
  for (int i = 0; i < 4; ++i) {
    int r = ty + i * 8;
    tile[r][tx] = ib[(long)(by * 32 + r) * inner + bx * 32 + tx];
  }
  __syncthreads();
#pragma unroll
  for (int i = 0; i < 4; ++i) {
    int r = ty + i * 8;
    ob[(long)(bx * 32 + r) * out_ld + by * 32 + tx] =
        __float2bfloat16(tile[tx][r]);
  }
}

// ---------- fused 3x [512,512] weight transpose -> bf16 ----------
__global__ __launch_bounds__(256) void transpose_w3(
    const float* __restrict__ w0, const float* __restrict__ w1,
    const float* __restrict__ w2,
    bf16* __restrict__ o0, bf16* __restrict__ o1, bf16* __restrict__ o2) {
  __shared__ float tile[32][33];
  const float* in;
  bf16* out;
  switch (blockIdx.z) {
    case 0: in = w0; out = o0; break;
    case 1: in = w1; out = o1; break;
    default: in = w2; out = o2; break;
  }
  const int bx = blockIdx.x, by = blockIdx.y;
  const int tx = threadIdx.x & 31, ty = threadIdx.x >> 5;
#pragma unroll
  for (int i = 0; i < 4; ++i) {
    int r = ty + i * 8;
    tile[r][tx] = in[(long)(by * 32 + r) * 512 + bx * 32 + tx];
  }
  __syncthreads();
#pragma unroll
  for (int i = 0; i < 4; ++i) {
    int r = ty + i * 8;
    out[(long)(bx * 32 + r) * 512 + by * 32 + tx] = __float2bfloat16(tile[tx][r]);
  }
}

// ---------- bias combine: bQc[o] = qb[o] + sum_e pb[e]*wq[e,o] ----------
__global__ __launch_bounds__(256) void bias_combine(
    const float* __restrict__ pb, const float* __restrict__ wq,
    const float* __restrict__ qb, float* __restrict__ out) {
  int o = blockIdx.x * 256 + threadIdx.x;
  if (o >= 512) return;
  float s = qb[o];
  for (int e = 0; e < 512; ++e) s += pb[e] * wq[e * 512 + o];
  out[o] = s;
}

// ---------- bias_out: bO[o] = pout_b[o] + sum_e poutw[o,512+e]*wv_b[e] ----------
__global__ __launch_bounds__(256) void bias_out(
    const float* __restrict__ poutw, const float* __restrict__ wvb,
    const float* __restrict__ pob, float* __restrict__ out) {
  int o = blockIdx.x * 256 + threadIdx.x;
  if (o >= 512) return;
  float s = pob[o];
  const float* row = poutw + (long)o * 1024 + 512;
  for (int e = 0; e < 512; ++e) s += row[e] * wvb[e];
  out[o] = s;
}

// ======================================================================
// 128x128 GEMM (r3/r4-verified: 0 bank conflicts, 4 blocks/CU).
// C[M,N] = alpha * A[M,K] @ B[N,K]^T (+bias).
// BIAS_MODE: 0 none, 1 per-col, 2 per-row.
// EPI: 0 plain, 1 v=exp(alpha*acc) + rowsum atomicAdd into sc.
// 1-D grid + chunked-bijective XCD remap; bn fastest.
// ======================================================================
template <int OUT_BF16, int BIAS_MODE, int EPI>
__global__ __launch_bounds__(256, 4) void gemm_bt_kernel(
    const bf16* __restrict__ A, long sAb, int lda,
    const bf16* __restrict__ B, long sBb, int ldb,
    void* __restrict__ Cp, long sCb, int ldc,
    const float* __restrict__ bias, float* __restrict__ sc, long scb,
    float alpha, int K, int lgx, int lgy) {
  __shared__ __align__(16) bf16 tA[128 * 64];
  __shared__ __align__(16) bf16 tB[128 * 64];

  const int nwg = gridDim.x;
  const int orig = blockIdx.x;
  const int q = nwg >> 3, r = nwg & 7;
  const int xcd = orig & 7, local = orig >> 3;
  const int wgid = (xcd < r ? xcd * (q + 1) : r * (q + 1) + (xcd - r) * q) + local;
  const int bn = wgid & ((1 << lgx) - 1);
  const int tmp = wgid >> lgx;
  const int bm = tmp & ((1 << lgy) - 1);
  const int bz = tmp >> lgy;

  const int t = threadIdx.x;
  const int w = t >> 6;
  const int lane = t & 63;

  const bf16* Ab = A + (long)bz * sAb;
  const bf16* Bb = B + (long)bz * sBb;

  const int srow = t >> 3;
  const int scol = ((t & 7) ^ (srow & 7)) * 8;
  const long a_base = (long)(bm * 128 + srow) * lda + scol;
  const long b_base = (long)(bn * 128 + srow) * ldb + scol;
  char* lA = (char*)tA + w * 1024;
  char* lB = (char*)tB + w * 1024;

  const int wr = w >> 1, wc = w & 1;
  const int r15 = lane & 15;
  const int khalf = lane >> 4;
  f32x4 acc[4][4] = {};

  for (int kt = 0; kt < K; kt += 64) {
#pragma unroll
    for (int i = 0; i < 4; ++i) {
      gld_lds16(Ab + a_base + (long)(i * 32) * lda + kt, lA + i * 4096);
      gld_lds16(Bb + b_base + (long)(i * 32) * ldb + kt, lB + i * 4096);
    }
    __syncthreads();
#pragma unroll
    for (int kk = 0; kk < 2; ++kk) {
      const int chunk = kk * 4 + khalf;
      s16x8 af[4], bg[4];
#pragma unroll
      for (int m = 0; m < 4; ++m) {
        const int row = wr * 64 + m * 16 + r15;
        af[m] = *(const s16x8*)(tA + row * 64 + ((chunk ^ (row & 7)) * 8));
      }
#pragma unroll
      for (int n = 0; n < 4; ++n) {
        const int row = wc * 64 + n * 16 + r15;
        bg[n] = *(const s16x8*)(tB + row * 64 + ((chunk ^ (row & 7)) * 8));
      }
#pragma unroll
      for (int m = 0; m < 4; ++m)
#pragma unroll
        for (int n = 0; n < 4; ++n)
          acc[m][n] = __builtin_amdgcn_mfma_f32_16x16x32_bf16(af[m], bg[n],
                                                              acc[m][n], 0, 0, 0);
    }
    __syncthreads();
  }

  // epilogue: C/D layout col = lane&15, row = (lane>>4)*4 + j  [m89-verified]
#pragma unroll
  for (int m = 0; m < 4; ++m) {
    const int rb = bm * 128 + wr * 64 + m * 16 + (lane >> 4) * 4;
    float rs[4] = {0.f, 0.f, 0.f, 0.f};
#pragma unroll
    for (int n = 0; n < 4; ++n) {
      const int col = bn * 128 + wc * 64 + n * 16 + r15;
      float bN = 0.f;
      if (BIAS_MODE == 1) bN = bias[col];
#pragma unroll
      for (int j = 0; j < 4; ++j) {
        const int row = rb + j;
        float v;
        if (EPI == 1) {
          v = __expf(acc[m][n][j] * alpha);
          rs[j] += v;
        } else {
          v = acc[m][n][j] * alpha;
          if (BIAS_MODE == 1) v += bN;
          if (BIAS_MODE == 2) v += bias[row];
        }
        const long off = (long)bz * sCb + (long)row * ldc + col;
        if (OUT_BF16)
          ((bf16*)Cp)[off] = __float2bfloat16(v);
        else
          ((float*)Cp)[off] = v;
      }
    }
    if (EPI == 1) {
#pragma unroll
      for (int j = 0; j < 4; ++j) {
        float s = rs[j];
#pragma unroll
        for (int sh = 1; sh < 16; sh <<= 1) s += __shfl_xor(s, sh, 64);
        if (r15 == 0) atomicAdd(sc + (long)bz * scb + rb + j, s);
      }
    }
  }
}

// ======================================================================
// Fused output GEMM:
//   out_b[o,hw] = (Vt2_b @ Sb_b^T)[o,hw] / rsum[b,hw]
//               + (poutw_L @ catL_b^T)[o,hw] + bias2[o]
// Dual-K accumulation in one kernel (K1=1024 over L, K2=512 over c).
// Same verified 128^2 core; fp32 output to d_out.
// grid 1-D = 32(bn) x 4(bm) x 8(bz), lgx=5, lgy=2.
// ======================================================================
__global__ __launch_bounds__(256, 4) void gemm_out_kernel(
    const bf16* __restrict__ A2, const bf16* __restrict__ B2,   // Vt2, Sb
    const bf16* __restrict__ A1, const bf16* __restrict__ B1,   // poutwL, catL
    float* __restrict__ C, const float* __restrict__ rsum,
    const float* __restrict__ bias2) {
  __shared__ __align__(16) bf16 tA[128 * 64];
  __shared__ __align__(16) bf16 tB[128 * 64];

  const int nwg = gridDim.x;
  const int orig = blockIdx.x;
  const int q = nwg >> 3, r = nwg & 7;
  const int xcd = orig & 7, local = orig >> 3;
  const int wgid = (xcd < r ? xcd * (q + 1) : r * (q + 1) + (xcd - r) * q) + local;
  const int bn = wgid & 31;
  const int tmp = wgid >> 5;
  const int bm = tmp & 3;
  const int bz = tmp >> 2;

  const int t = threadIdx.x;
  const int w = t >> 6;
  const int lane = t & 63;

  const int srow = t >> 3;
  const int scol = ((t & 7) ^ (srow & 7)) * 8;
  char* lA = (char*)tA + w * 1024;
  char* lB = (char*)tB + w * 1024;

  const int wr = w >> 1, wc = w & 1;
  const int r15 = lane & 15;
  const int khalf = lane >> 4;
  f32x4 acc[4][4] = {};

  // ---- pass 1: Vt2 [512,1024] @ Sb [4096,1024]^T, K1=1024 ----
  {
    const bf16* Ab = A2 + (long)bz * (512 * 1024);
    const bf16* Bb = B2 + (long)bz * ((long)4096 * 1024);
    const long a_base = (long)(bm * 128 + srow) * 1024 + scol;
    const long b_base = (long)(bn * 128 + srow) * 1024 + scol;
    for (int kt = 0; kt < 1024; kt += 64) {
#pragma unroll
      for (int i = 0; i < 4; ++i) {
        gld_lds16(Ab + a_base + (long)(i * 32) * 1024 + kt, lA + i * 4096);
        gld_lds16(Bb + b_base + (long)(i * 32) * 1024 + kt, lB + i * 4096);
      }
      __syncthreads();
#pragma unroll
      for (int kk = 0; kk < 2; ++kk) {
        const int chunk = kk * 4 + khalf;
        s16x8 af[4], bg[4];
#pragma unroll
        for (int m = 0; m < 4; ++m) {
          const int row = wr * 64 + m * 16 + r15;
          af[m] = *(const s16x8*)(tA + row * 64 + ((chunk ^ (row & 7)) * 8));
        }
#pragma unroll
        for (int n = 0; n < 4; ++n) {
          const int row = wc * 64 + n * 16 + r15;
          bg[n] = *(const s16x8*)(tB + row * 64 + ((chunk ^ (row & 7)) * 8));
        }
#pragma unroll
        for (int m = 0; m < 4; ++m)
#pragma unroll
          for (int n = 0; n < 4; ++n)
            acc[m][n] = __builtin_amdgcn_mfma_f32_16x16x32_bf16(
                af[m], bg[n], acc[m][n], 0, 0, 0);
      }
      __syncthreads();
    }
  }

  // ---- per-column softmax normalization of the attention term ----
#pragma unroll
  for (int n = 0; n < 4; ++n) {
    const int col = bn * 128 + wc * 64 + n * 16 + r15;
    const float rin = 1.0f / rsum[(long)bz * 4096 + col];
#pragma unroll
    for (int m = 0; m < 4; ++m)
#pragma unroll
      for (int j = 0; j < 4; ++j) acc[m][n][j] *= rin;
  }

  // ---- pass 2: poutw_L [512,512] @ catL [4096,512]^T, K2=512 ----
  {
    const bf16* Ab = A1;  // lda 1024, left half (cols 0..511)
    const bf16* Bb = B1 + (long)bz * ((long)4096 * 512);
    const long a_base = (long)(bm * 128 + srow) * 1024 + scol;
    const long b_base = (long)(bn * 128 + srow) * 512 + scol;
    for (int kt = 0; kt < 512; kt += 64) {
#pragma unroll
      for (int i = 0; i < 4; ++i) {
        gld_lds16(Ab + a_base + (long)(i * 32) * 1024 + kt, lA + i * 4096);
        gld_lds16(Bb + b_base + (long)(i * 32) * 512 + kt, lB + i * 4096);
      }
      __syncthreads();
#pragma unroll
      for (int kk = 0; kk < 2; ++kk) {
        const int chunk = kk * 4 + khalf;
        s16x8 af[4], bg[4];
#pragma unroll
        for (int m = 0; m < 4; ++m) {
          const int row = wr * 64 + m * 16 + r15;
          af[m] = *(const s16x8*)(tA + row * 64 + ((chunk ^ (row & 7)) * 8));
        }
#pragma unroll
        for (int n = 0; n < 4; ++n) {
          const int row = wc * 64 + n * 16 + r15;
          bg[n] = *(const s16x8*)(tB + row * 64 + ((chunk ^ (row & 7)) * 8));
        }
#pragma unroll
        for (int m = 0; m < 4; ++m)
#pragma unroll
          for (int n = 0; n < 4; ++n)
            acc[m][n] = __builtin_amdgcn_mfma_f32_16x16x32_bf16(
                af[m], bg[n], acc[m][n], 0, 0, 0);
      }
      __syncthreads();
    }
  }

  // ---- epilogue ----
#pragma unroll
  for (int m = 0; m < 4; ++m) {
    const int rb = bm * 128 + wr * 64 + m * 16 + (lane >> 4) * 4;
#pragma unroll
    for (int n = 0; n < 4; ++n) {
      const int col = bn * 128 + wc * 64 + n * 16 + r15;
#pragma unroll
      for (int j = 0; j < 4; ++j) {
        const int row = rb + j;
        C[(long)bz * (512L * 4096) + (long)row * 4096 + col] =
            acc[m][n][j] + bias2[row];
      }
    }
  }
}

// ---------- host ----------
extern "C" void kernel_launch(void* const* d_in, const int* in_sizes, int n_in,
                              void* d_out, int out_size, void* d_ws, size_t ws_size,
                              hipStream_t stream) {
  const float* input   = (const float*)d_in[0];   // [8,512,4096]
  const float* context = (const float*)d_in[1];   // [8,512,1024]
  const float* pin_w   = (const float*)d_in[2];   // [512 e,512 c]
  const float* pin_b   = (const float*)d_in[3];
  const float* wq_w    = (const float*)d_in[4];   // [512 e,512 o]
  const float* wq_b    = (const float*)d_in[5];
  const float* wk_w    = (const float*)d_in[6];
  const float* wk_b    = (const float*)d_in[7];
  const float* wv_w    = (const float*)d_in[8];   // [512 c,512 e]
  const float* wv_b    = (const float*)d_in[9];
  const float* pout_w  = (const float*)d_in[10];  // [512 o,1024 c]
  const float* pout_b  = (const float*)d_in[11];

  char* ws = (char*)d_ws;
  size_t off = 0;
  auto alloc = [&](size_t bytes) -> void* {
    void* p = ws + off;
    off += (bytes + 255) & ~(size_t)255;
    return p;
  };
  bf16* poutw = (bf16*)alloc((size_t)512 * 1024 * 2);
  bf16* wvC  = (bf16*)alloc((size_t)512 * 512 * 2);
  bf16* wqT  = (bf16*)alloc((size_t)512 * 512 * 2);
  bf16* wkT  = (bf16*)alloc((size_t)512 * 512 * 2);
  bf16* pinT = (bf16*)alloc((size_t)512 * 512 * 2);
  bf16* WQc  = (bf16*)alloc((size_t)512 * 512 * 2);
  bf16* Wv2  = (bf16*)alloc((size_t)512 * 512 * 2);
  float* bQc = (float*)alloc((size_t)512 * 4);
  float* bO  = (float*)alloc((size_t)512 * 4);
  bf16* catL = (bf16*)alloc((size_t)32768 * 512 * 2);   // input^T per batch
  bf16* ctxt = (bf16*)alloc((size_t)8192 * 512 * 2);    // [b*1024, 512]
  bf16* Qb   = (bf16*)alloc((size_t)32768 * 512 * 2);
  bf16* Kmb  = (bf16*)alloc((size_t)8192 * 512 * 2);
  bf16* Vt2  = (bf16*)alloc((size_t)8 * 512 * 1024 * 2);  // [b][512 o][1024 L]
  bf16* Sb   = (bf16*)alloc((size_t)8 * 4096 * 1024 * 2); // expS
  float* rsum = (float*)alloc((size_t)32768 * 4);

  dim3 blk(256);

  // weight prep
  convert_f32_bf16<<<2048, blk, 0, stream>>>(pout_w, poutw, 512 * 1024);
  convert_f32_bf16<<<1024, blk, 0, stream>>>(wv_w, wvC, 512 * 512);
  zero_f32<<<128, blk, 0, stream>>>(rsum, 32768);
  transpose_w3<<<dim3(16, 16, 3), blk, 0, stream>>>(wq_w, wk_w, pin_w,
                                                    wqT, wkT, pinT);
  bias_combine<<<2, blk, 0, stream>>>(pin_b, wq_w, wq_b, bQc);
  bias_out<<<2, blk, 0, stream>>>(pout_w, wv_b, pout_b, bO);
  // input -> catL [b][4096 hw][512 c]
  transpose_f32_to_bf16<<<dim3(128, 16, 8), blk, 0, stream>>>(
      input, catL, 4096, (long)512 * 4096, (long)4096 * 512, 512);
  // context -> ctxt [b][1024 L][512 c]
  transpose_f32_to_bf16<<<dim3(32, 16, 8), blk, 0, stream>>>(
      context, ctxt, 1024, (long)512 * 1024, (long)1024 * 512, 512);

  const float scale = 0.04419417382415922f;  // 512^-0.5

  // WQc[o,c] = sum_e wq[e,o]*pin_w[e,c]   (grid 4x4)
  gemm_bt_kernel<1, 0, 0><<<dim3(16), blk, 0, stream>>>(
      wqT, 0, 512, pinT, 0, 512, WQc, 0, 512, nullptr, nullptr, 0, 1.f, 512, 2, 2);
  // Wv2[o,c] = sum_e poutw[o,512+e]*wv[c,e]   (grid 4x4)
  gemm_bt_kernel<1, 0, 0><<<dim3(16), blk, 0, stream>>>(
      poutw + 512, 0, 1024, wvC, 0, 512, Wv2, 0, 512, nullptr, nullptr, 0, 1.f,
      512, 2, 2);
  // K = ctxt @ wkT^T + wk_b  [8192,512]  (grid 4x64)
  gemm_bt_kernel<1, 1, 0><<<dim3(256), blk, 0, stream>>>(
      ctxt, 0, 512, wkT, 0, 512, Kmb, 0, 512, wk_b, nullptr, 0, 1.f, 512, 2, 6);
  // Vt2_b = Wv2 @ ctx_b^T  [8][512,1024]  (grid 8x4x8)
  gemm_bt_kernel<1, 0, 0><<<dim3(256), blk, 0, stream>>>(
      Wv2, 0, 512, ctxt, (long)1024 * 512, 512, Vt2, (long)512 * 1024, 1024,
      nullptr, nullptr, 0, 1.f, 512, 3, 2);
  // Q = catL @ WQc^T + bQc   [32768,512]  (grid 4x256)
  gemm_bt_kernel<1, 1, 0><<<dim3(1024), blk, 0, stream>>>(
      catL, 0, 512, WQc, 0, 512, Qb, 0, 512, bQc, nullptr, 0, 1.f, 512, 2, 8);
  // expS_b = exp(scale*Q_b@K_b^T), rowsum->rsum  [8][4096,1024] (grid 8x32x8)
  gemm_bt_kernel<1, 0, 1><<<dim3(2048), blk, 0, stream>>>(
      Qb, (long)4096 * 512, 512, Kmb, (long)1024 * 512, 512, Sb,
      (long)4096 * 1024, 1024, nullptr, rsum, 4096, scale, 512, 3, 5);
  // fused out = Vt2@Sb^T/rsum + poutwL@catL^T + bO -> d_out (grid 32x4x8)
  gemm_out_kernel<<<dim3(1024), blk, 0, stream>>>(
      Vt2, Sb, poutw, catL, (float*)d_out, rsum, bO);
}